// Round 4
// baseline (37.387 us; speedup 1.0000x reference)
//
#include <hip/hip_runtime.h>
#include <hip/hip_bf16.h>

#define N_NODES 4096
#define IN_FEAT 128
#define OUT_FEAT 64
#define NHEAD 4
#define HID 256           // NHEAD * OUT_FEAT
#define NEG_SLOPE 0.2f
#define MAXC 256          // per-node neighbor cap (expected max degree ~75)
#define GEMM_BLOCKS 256   // 64 row-blocks x 4 col-blocks (64x64 output tiles)
#define SCAN_BLOCKS 1024  // 4 waves/block, one adj ROW PER WAVE

typedef float f4 __attribute__((ext_vector_type(4)));

// ---------------------------------------------------------------------------
// Kernel 1 (heterogeneous): blocks 0..255 = register-tiled GEMM (64x64 tile,
// 4x4 per thread) + fused attn reductions; blocks 256..1279 scan adj rows,
// ONE ROW PER WAVE: 16 float4 loads/lane (16KB in flight per wave), u64 lane
// mask, wave-local prefix + scatter. No barriers, no LDS in the scan path.
// ---------------------------------------------------------------------------
__global__ __launch_bounds__(256) void k_prep(
    const float* __restrict__ x, const float* __restrict__ adj,
    const float* __restrict__ W, const float* __restrict__ a,
    float* __restrict__ h, float* __restrict__ attn_src,
    float* __restrict__ attn_tgt,
    unsigned short* __restrict__ nbrs, int* __restrict__ deg)
{
    __shared__ f4 xs4[64][32];        // x tile, XOR-swizzled along kq (32KB)
    __shared__ float red_s[4][64];    // cross-wave attn partials
    __shared__ float red_t[4][64];

    const int t = threadIdx.x;
    const int lane = t & 63;
    const int wv = t >> 6;

    if (blockIdx.x < GEMM_BLOCKS) {
        const int rb = blockIdx.x >> 2;        // row block 0..63
        const int cb = blockIdx.x & 3;         // col block == head
        const int row0 = rb * 64;
        const int tc4 = (t >> 4) * 4;          // this thread's 4 cols (within head)
        const int c0 = cb * 64 + tc4;
        const int tr = t & 15;                 // row group (rows tr*4 .. tr*4+3)

        // ---- stage x tile (64 rows x 128 k), swizzled: xs4[r][kq ^ (r>>2 & 7)]
        {
            const f4* xg = reinterpret_cast<const f4*>(x) + (size_t)row0 * 32;
            const int kq = t & 31;
            #pragma unroll
            for (int it = 0; it < 8; ++it) {
                const int r = it * 8 + (t >> 5);
                xs4[r][kq ^ ((r >> 2) & 7)] = xg[r * 32 + kq];
            }
        }
        __syncthreads();

        f4 acc[4] = {};   // acc[j] = float4 over 4 cols, j = row within group

        for (int kq = 0; kq < 32; ++kq) {      // 4 k's per iteration
            f4 wvv[4];                         // W[4k+kk][c0..c0+3], per-lane distinct
            #pragma unroll
            for (int kk = 0; kk < 4; ++kk)
                wvv[kk] = *reinterpret_cast<const f4*>(W + (kq * 4 + kk) * HID + c0);
            f4 xv[4];                          // xs[tr*4+j][4kq..4kq+3]
            #pragma unroll
            for (int j = 0; j < 4; ++j)
                xv[j] = xs4[tr * 4 + j][kq ^ (tr & 7)];
            #pragma unroll
            for (int kk = 0; kk < 4; ++kk)
                #pragma unroll
                for (int j = 0; j < 4; ++j)
                    acc[j] += xv[j][kk] * wvv[kk];
        }

        // ---- write h (f32) ----
        #pragma unroll
        for (int j = 0; j < 4; ++j) {
            const int row = row0 + tr * 4 + j;
            *reinterpret_cast<f4*>(h + (size_t)row * HID + c0) = acc[j];
        }

        // ---- fused attn reductions ----
        const f4 asv = *reinterpret_cast<const f4*>(a + cb * 2 * OUT_FEAT + tc4);
        const f4 atv = *reinterpret_cast<const f4*>(a + cb * 2 * OUT_FEAT + OUT_FEAT + tc4);
        #pragma unroll
        for (int j = 0; j < 4; ++j) {
            float s = acc[j][0] * asv[0] + acc[j][1] * asv[1]
                    + acc[j][2] * asv[2] + acc[j][3] * asv[3];
            float g = acc[j][0] * atv[0] + acc[j][1] * atv[1]
                    + acc[j][2] * atv[2] + acc[j][3] * atv[3];
            s += __shfl_xor(s, 16, 64); s += __shfl_xor(s, 32, 64);
            g += __shfl_xor(g, 16, 64); g += __shfl_xor(g, 32, 64);
            if (((t >> 4) & 3) == 0) {          // one rep per (wave, tr)
                red_s[wv][tr * 4 + j] = s;
                red_t[wv][tr * 4 + j] = g;
            }
        }
        __syncthreads();
        if (t < 64) {
            const float s = red_s[0][t] + red_s[1][t] + red_s[2][t] + red_s[3][t];
            const float g = red_t[0][t] + red_t[1][t] + red_t[2][t] + red_t[3][t];
            attn_src[(row0 + t) * NHEAD + cb] = s;
            attn_tgt[(row0 + t) * NHEAD + cb] = g;
        }
    } else {
        // ---- adj scan: ONE ROW PER WAVE ----
        const int i = (blockIdx.x - GEMM_BLOCKS) * 4 + wv;   // row 0..4095

        // 16 float4 loads per lane, all issued before use (16KB/wave in flight).
        // Element j = u*256 + lane*4 + c  -> per-lane bit index u*4 + c (u64).
        const float4* arow = reinterpret_cast<const float4*>(adj + (size_t)i * N_NODES);
        float4 v[16];
        #pragma unroll
        for (int u = 0; u < 16; ++u) v[u] = arow[u * 64 + lane];

        unsigned long long m = 0ull;
        #pragma unroll
        for (int u = 0; u < 16; ++u) {
            const int jb = u * 256 + lane * 4;
            if (v[u].x != 0.f || (jb + 0) == i) m |= 1ull << (u * 4 + 0);
            if (v[u].y != 0.f || (jb + 1) == i) m |= 1ull << (u * 4 + 1);
            if (v[u].z != 0.f || (jb + 2) == i) m |= 1ull << (u * 4 + 2);
            if (v[u].w != 0.f || (jb + 3) == i) m |= 1ull << (u * 4 + 3);
        }
        const int cnt = __popcll(m);

        // wave-local inclusive prefix sum
        int incl = cnt;
        #pragma unroll
        for (int d = 1; d < 64; d <<= 1) {
            int u2 = __shfl_up(incl, d, 64);
            if (lane >= d) incl += u2;
        }
        int off = incl - cnt;                       // exclusive offset
        if (lane == 63) deg[i] = (incl < MAXC) ? incl : MAXC;

        unsigned short* nl = nbrs + (size_t)i * MAXC;
        unsigned long long mm = m;
        while (mm) {
            const int b = __ffsll((unsigned long long)mm) - 1;
            mm &= mm - 1;
            const int j = ((b >> 2) * 256) + lane * 4 + (b & 3);
            if (off < MAXC) nl[off] = (unsigned short)j;
            ++off;
        }
    }
}

// ---------------------------------------------------------------------------
// Kernel 2: per node i — softmax over neighbor list + aggregation
// (4 neighbors / iteration, float4 per lane). Wave wv owns head wv.
// ---------------------------------------------------------------------------
__global__ __launch_bounds__(256) void k_agg(
    const unsigned short* __restrict__ nbrs, const int* __restrict__ deg,
    const float* __restrict__ h, const float* __restrict__ attn_src,
    const float* __restrict__ attn_tgt, float* __restrict__ out)
{
    __shared__ float p[NHEAD][MAXC];
    __shared__ unsigned short nl[MAXC];

    const int i = blockIdx.x;
    const int t = threadIdx.x;
    const int lane = t & 63;
    const int head = t >> 6;

    const int d = deg[i];
    nl[t] = (t < d) ? nbrs[(size_t)i * MAXC + t] : (unsigned short)0;
    __syncthreads();

    // ---- softmax (wave-local per head) ----
    const float srcv = attn_src[i * NHEAD + head];
    const int rnd = (d + 3) & ~3;
    float lmax = -1e30f;
    for (int idx = lane; idx < rnd; idx += 64) {
        if (idx < d) {
            float e = srcv + attn_tgt[nl[idx] * NHEAD + head];
            e = (e > 0.f) ? e : NEG_SLOPE * e;
            p[head][idx] = e;
            lmax = fmaxf(lmax, e);
        } else {
            p[head][idx] = 0.f;   // padding consumed with weight 0 below
        }
    }
    #pragma unroll
    for (int s = 32; s; s >>= 1) lmax = fmaxf(lmax, __shfl_xor(lmax, s, 64));
    float ssum = 0.f;
    for (int idx = lane; idx < d; idx += 64) {
        float pe = __expf(p[head][idx] - lmax);
        p[head][idx] = pe;
        ssum += pe;
    }
    #pragma unroll
    for (int s = 32; s; s >>= 1) ssum += __shfl_xor(ssum, s, 64);
    const float inv = 1.0f / ssum;   // d >= 1 always (self loop)

    // ---- aggregation: 4 neighbors per iteration ----
    const int g  = lane >> 4;        // neighbor sub-slot 0..3
    const int f4i = lane & 15;       // float4 feature chunk 0..15
    const float* hbase = h + head * OUT_FEAT + f4i * 4;
    float4 acc = {0.f, 0.f, 0.f, 0.f};
    for (int idx4 = 0; idx4 < d; idx4 += 4) {
        const int j   = nl[idx4 + g];          // LDS broadcast (pad -> 0)
        const float pw = p[head][idx4 + g];    // pad -> 0
        const float4 hv = *reinterpret_cast<const float4*>(hbase + (size_t)j * HID);
        acc.x += pw * hv.x; acc.y += pw * hv.y;
        acc.z += pw * hv.z; acc.w += pw * hv.w;
    }
    #pragma unroll
    for (int s = 16; s <= 32; s <<= 1) {
        acc.x += __shfl_xor(acc.x, s, 64);
        acc.y += __shfl_xor(acc.y, s, 64);
        acc.z += __shfl_xor(acc.z, s, 64);
        acc.w += __shfl_xor(acc.w, s, 64);
    }
    if (g == 0) {
        float4 o = {acc.x * inv, acc.y * inv, acc.z * inv, acc.w * inv};
        *reinterpret_cast<float4*>(out + (size_t)i * HID + head * OUT_FEAT + f4i * 4) = o;
    }
}

// ---------------------------------------------------------------------------
extern "C" void kernel_launch(void* const* d_in, const int* in_sizes, int n_in,
                              void* d_out, int out_size, void* d_ws, size_t ws_size,
                              hipStream_t stream)
{
    const float* x   = (const float*)d_in[0];   // (4096,128)
    const float* adj = (const float*)d_in[1];   // (4096,4096)
    const float* W   = (const float*)d_in[2];   // (128,256)
    const float* a   = (const float*)d_in[3];   // (4,128)
    float* out = (float*)d_out;                 // (4096,256)

    char* ws = (char*)d_ws;
    float* h         = (float*)ws;                                  // 4 MB
    float* attn_src  = (float*)(ws + (size_t)N_NODES * HID * 4);    // 64 KB
    float* attn_tgt  = attn_src + (size_t)N_NODES * NHEAD;          // 64 KB
    unsigned short* nbrs = (unsigned short*)(attn_tgt + (size_t)N_NODES * NHEAD); // 2 MB
    int* deg         = (int*)(nbrs + (size_t)N_NODES * MAXC);       // 16 KB

    k_prep<<<GEMM_BLOCKS + SCAN_BLOCKS, 256, 0, stream>>>(
        x, adj, W, a, h, attn_src, attn_tgt, nbrs, deg);
    k_agg<<<N_NODES, 256, 0, stream>>>(nbrs, deg, h, attn_src, attn_tgt, out);
}